// Round 11
// baseline (152.141 us; speedup 1.0000x reference)
//
#include <hip/hip_runtime.h>
#include <hip/hip_bf16.h>

#define NUM_NODES 50000
#define NODE_DIM 32
#define EDGE_DIM 7
#define HIDDEN_DIM 64
#define NUM_EDGES 200000

typedef __attribute__((ext_vector_type(8))) short bf16x8;
typedef __attribute__((ext_vector_type(4))) float f32x4;
typedef _Float16 h2 __attribute__((ext_vector_type(2)));

#if defined(__has_builtin)
#if __has_builtin(__builtin_amdgcn_fdot2)
#define HAVE_FDOT2 1
#endif
#endif
#ifndef HAVE_FDOT2
#define HAVE_FDOT2 0
#endif

__device__ inline unsigned f2bf(float f) {
    union { float f; unsigned u; } x; x.f = f;
    return (x.u + 0x7FFFu + ((x.u >> 16) & 1u)) >> 16;   // RNE
}
__device__ inline unsigned pack2bf(float a, float b) {
    return f2bf(a) | (f2bf(b) << 16);
}
__device__ inline h2 u2h(unsigned u) {
    union { unsigned u; h2 h; } c; c.u = u; return c.h;
}
__device__ inline unsigned h2u(h2 h) {
    union { h2 h; unsigned u; } c; c.h = h; return c.u;
}

// ---------------------------------------------------------------------------
// K_P: per-lane B fragments for the classifier GEMM (bf16, verified r4+).
// ---------------------------------------------------------------------------
__global__ __launch_bounds__(256) void k_prep(const float* __restrict__ w_e1,
                                              const float* __restrict__ b_e1,
                                              ushort* __restrict__ bfrag) {
    int u = blockIdx.x * blockDim.x + threadIdx.x;
    if (u < 5 * 4 * 64 * 8) {
        int j     = u & 7;
        int lane  = (u >> 3) & 63;
        int ntile = (u >> 9) & 3;
        int kstep = u >> 11;
        int k = kstep * 32 + (lane >> 4) * 8 + j;
        int o = ntile * 16 + (lane & 15);
        float v = (k < 135) ? w_e1[k * 64 + o] : ((k == 135) ? b_e1[o] : 0.f);
        bfrag[u] = (ushort)f2bf(v);
    }
}

// ---------------------------------------------------------------------------
// K_A: agg[n][o] = conv_bias[o] + sum_i x[n][i] * root_w[i][o]   (verified)
// ---------------------------------------------------------------------------
__global__ __launch_bounds__(256) void k_init2(const float* __restrict__ x,
                                               const float* __restrict__ root_w,
                                               const float* __restrict__ conv_bias,
                                               float* __restrict__ agg) {
    __shared__ float rw[NODE_DIM * HIDDEN_DIM];   // 8KB
    __shared__ float cb[HIDDEN_DIM];
    __shared__ float xS[128 * NODE_DIM];          // 16KB
    for (int t = threadIdx.x; t < NODE_DIM * HIDDEN_DIM; t += 256) rw[t] = root_w[t];
    if (threadIdx.x < HIDDEN_DIM) cb[threadIdx.x] = conv_bias[threadIdx.x];
    const int nb = blockIdx.x * 128;
    {
        const float4* xg = (const float4*)x;
        float4* xs4 = (float4*)xS;
        #pragma unroll
        for (int r = 0; r < 4; ++r) {
            int t = r * 256 + threadIdx.x;
            int gi = nb * (NODE_DIM / 4) + t;
            xs4[t] = (gi < NUM_NODES * (NODE_DIM / 4)) ? xg[gi] : make_float4(0.f, 0.f, 0.f, 0.f);
        }
    }
    __syncthreads();
    const int lane = threadIdx.x & 63;
    const int w    = threadIdx.x >> 6;
    for (int r = 0; r < 32; ++r) {
        const int n = nb + w * 32 + r;
        if (n >= NUM_NODES) break;                 // wave-uniform
        float acc = cb[lane];
        const float* xr = &xS[(w * 32 + r) * NODE_DIM];
        #pragma unroll
        for (int i = 0; i < NODE_DIM; ++i)
            acc = fmaf(xr[i], rw[i * HIDDEN_DIM + lane], acc);
        agg[n * HIDDEN_DIM + lane] = acc;
    }
}

// ---------------------------------------------------------------------------
// K_B v8 (r10-verbatim body; regridded + wider unroll):
//  - weights+bias packed f16 in ONE 32KB LDS plane [32][64] of uint4;
//    conflict-free b128 reads (measured 0 conflicts in r10);
//  - MLP inner product via v_dot2_f32_f16 (f32 accumulate);
//  - no x/ea LDS staging: src ids -> SGPR via readfirstlane, x rows as
//    uniform float4 (s_load path), ea as uniform scalars;
//  - MB=8 edges/wave; grid = 3125 blocks so all 25000 groups get their own
//    wave (r10 limiter: only 4096 waves dispatched -> 31.7% occupancy).
// ---------------------------------------------------------------------------
#define MBX 8
__global__ __launch_bounds__(512) void k_msg8(const int* __restrict__ ei,
                                              const float* __restrict__ ea,
                                              const float* __restrict__ x,
                                              const float* __restrict__ w_nn,
                                              const float* __restrict__ b_nn,
                                              float* __restrict__ agg) {
    __shared__ uint4 wHu[NODE_DIM * HIDDEN_DIM];   // 2048 x 16B = 32KB
    for (int c = threadIdx.x; c < NODE_DIM * HIDDEN_DIM; c += 512) {
        h2 p0, p1, p2, p3;
        p0[0] = (_Float16)w_nn[0 * 2048 + c]; p0[1] = (_Float16)w_nn[1 * 2048 + c];
        p1[0] = (_Float16)w_nn[2 * 2048 + c]; p1[1] = (_Float16)w_nn[3 * 2048 + c];
        p2[0] = (_Float16)w_nn[4 * 2048 + c]; p2[1] = (_Float16)w_nn[5 * 2048 + c];
        p3[0] = (_Float16)w_nn[6 * 2048 + c]; p3[1] = (_Float16)b_nn[c];
        uint4 v; v.x = h2u(p0); v.y = h2u(p1); v.z = h2u(p2); v.w = h2u(p3);
        wHu[c] = v;
    }
    __syncthreads();

    const int lane   = threadIdx.x & 63;
    const int wave   = (blockIdx.x * blockDim.x + threadIdx.x) >> 6;
    const int nwaves = (gridDim.x * blockDim.x) >> 6;

    for (int e0 = wave * MBX; e0 < NUM_EDGES; e0 += nwaves * MBX) {
        // NUM_EDGES % 8 == 0, no tail.
        int sA[MBX];
        #pragma unroll
        for (int m = 0; m < MBX; ++m)
            sA[m] = __builtin_amdgcn_readfirstlane(ei[e0 + m]);   // uniform -> SGPR

#if HAVE_FDOT2
        h2 ev[MBX][4];
        #pragma unroll
        for (int m = 0; m < MBX; ++m) {
            const float* ep = ea + (size_t)(e0 + m) * EDGE_DIM;
            ev[m][0][0] = (_Float16)ep[0]; ev[m][0][1] = (_Float16)ep[1];
            ev[m][1][0] = (_Float16)ep[2]; ev[m][1][1] = (_Float16)ep[3];
            ev[m][2][0] = (_Float16)ep[4]; ev[m][2][1] = (_Float16)ep[5];
            ev[m][3][0] = (_Float16)ep[6]; ev[m][3][1] = (_Float16)1.0f;
        }
#else
        float evf[MBX][7];
        #pragma unroll
        for (int m = 0; m < MBX; ++m) {
            const float* ep = ea + (size_t)(e0 + m) * EDGE_DIM;
            #pragma unroll
            for (int k = 0; k < 7; ++k) evf[m][k] = ep[k];
        }
#endif

        float acc[MBX];
        #pragma unroll
        for (int m = 0; m < MBX; ++m) acc[m] = 0.f;

        #pragma unroll 4
        for (int i4 = 0; i4 < NODE_DIM / 4; ++i4) {
            float4 xv[MBX];
            #pragma unroll
            for (int m = 0; m < MBX; ++m)
                xv[m] = *(const float4*)(x + (size_t)sA[m] * NODE_DIM + i4 * 4); // uniform addr
            #pragma unroll
            for (int ii = 0; ii < 4; ++ii) {
                const int i = i4 * 4 + ii;
                const uint4 wv = wHu[i * HIDDEN_DIM + lane];     // b128, conflict-free
#if HAVE_FDOT2
                const h2 w0 = u2h(wv.x), w1 = u2h(wv.y), w2 = u2h(wv.z), w3 = u2h(wv.w);
                #pragma unroll
                for (int m = 0; m < MBX; ++m) {
                    float t = __builtin_amdgcn_fdot2(ev[m][0], w0,
                              __builtin_amdgcn_fdot2(ev[m][1], w1,
                              __builtin_amdgcn_fdot2(ev[m][2], w2,
                              __builtin_amdgcn_fdot2(ev[m][3], w3, 0.f, false),
                              false), false), false);
                    t = fmaxf(t, 0.f);
                    const float xc = (ii == 0) ? xv[m].x : (ii == 1) ? xv[m].y
                                   : (ii == 2) ? xv[m].z : xv[m].w;
                    acc[m] = fmaf(t, xc, acc[m]);
                }
#else
                float wf[8];
                { h2 a = u2h(wv.x), b = u2h(wv.y), c = u2h(wv.z), d = u2h(wv.w);
                  wf[0] = (float)a[0]; wf[1] = (float)a[1];
                  wf[2] = (float)b[0]; wf[3] = (float)b[1];
                  wf[4] = (float)c[0]; wf[5] = (float)c[1];
                  wf[6] = (float)d[0]; wf[7] = (float)d[1]; }
                #pragma unroll
                for (int m = 0; m < MBX; ++m) {
                    float t = wf[7];
                    #pragma unroll
                    for (int k = 0; k < 7; ++k) t = fmaf(evf[m][k], wf[k], t);
                    t = fmaxf(t, 0.f);
                    const float xc = (ii == 0) ? xv[m].x : (ii == 1) ? xv[m].y
                                   : (ii == 2) ? xv[m].z : xv[m].w;
                    acc[m] = fmaf(t, xc, acc[m]);
                }
#endif
            }
        }

        #pragma unroll
        for (int m = 0; m < MBX; ++m) {
            const int d = ei[NUM_EDGES + e0 + m];
            atomicAdd(&agg[(size_t)d * HIDDEN_DIM + lane], acc[m]);
        }
    }
}

// ---------------------------------------------------------------------------
// K_C v3: classifier as bf16 MFMA GEMM (verbatim, passing since round 4).
// ---------------------------------------------------------------------------
#define ASTRIDE 168
__global__ __launch_bounds__(256) void k_edge3(const int* __restrict__ ei,
                                               const float* __restrict__ ea,
                                               const float* __restrict__ agg,
                                               const ushort* __restrict__ bfrag,
                                               const float* __restrict__ w_e2,
                                               const float* __restrict__ b_e2,
                                               float* __restrict__ out) {
    __shared__ ushort aS[64 * ASTRIDE];   // 21504B
    __shared__ ushort bS[5 * 4 * 64 * 8]; // 20480B
    __shared__ float  w2S[128];
    {
        const uint4* g = (const uint4*)bfrag;
        uint4* s = (uint4*)bS;
        for (int t = threadIdx.x; t < 1280; t += 256) s[t] = g[t];
        if (threadIdx.x < 128) w2S[threadIdx.x] = w_e2[threadIdx.x];
    }
    const int e0 = blockIdx.x * 64;
    {
        const int el = threadIdx.x >> 2;
        const int q  = threadIdx.x & 3;
        const int e  = e0 + el;
        const int src = ei[e], dst = ei[NUM_EDGES + e];
        const float4* ps = (const float4*)(agg + (size_t)src * HIDDEN_DIM + q * 16);
        const float4* pd = (const float4*)(agg + (size_t)dst * HIDDEN_DIM + q * 16);
        unsigned* arow = (unsigned*)(aS + el * ASTRIDE);
        #pragma unroll
        for (int i = 0; i < 4; ++i) {
            float4 s = ps[i];
            arow[q * 8 + i * 2 + 0] = pack2bf(fmaxf(s.x, 0.f), fmaxf(s.y, 0.f));
            arow[q * 8 + i * 2 + 1] = pack2bf(fmaxf(s.z, 0.f), fmaxf(s.w, 0.f));
        }
        #pragma unroll
        for (int i = 0; i < 4; ++i) {
            float4 d = pd[i];
            arow[32 + q * 8 + i * 2 + 0] = pack2bf(fmaxf(d.x, 0.f), fmaxf(d.y, 0.f));
            arow[32 + q * 8 + i * 2 + 1] = pack2bf(fmaxf(d.z, 0.f), fmaxf(d.w, 0.f));
        }
        if (q == 0) {
            float ev[8];
            #pragma unroll
            for (int k = 0; k < EDGE_DIM; ++k) ev[k] = ea[e * EDGE_DIM + k];
            ev[7] = 1.0f;
            #pragma unroll
            for (int i = 0; i < 4; ++i)
                arow[64 + i] = pack2bf(ev[2 * i], ev[2 * i + 1]);
        } else {
            unsigned* z = arow + 64 + q * 4;
            z[0] = 0u; z[1] = 0u; z[2] = 0u; z[3] = 0u;
        }
    }
    __syncthreads();

    const int lane = threadIdx.x & 63;
    const int w    = threadIdx.x >> 6;
    f32x4 acc[4];
    #pragma unroll
    for (int nt = 0; nt < 4; ++nt) acc[nt] = (f32x4){0.f, 0.f, 0.f, 0.f};

    const ushort* arow = aS + (w * 16 + (lane & 15)) * ASTRIDE + (lane >> 4) * 8;
    #pragma unroll
    for (int ks = 0; ks < 5; ++ks) {
        bf16x8 af = *(const bf16x8*)(arow + ks * 32);
        #pragma unroll
        for (int nt = 0; nt < 4; ++nt) {
            bf16x8 bf = *(const bf16x8*)(bS + ((ks * 4 + nt) * 64 + lane) * 8);
            acc[nt] = __builtin_amdgcn_mfma_f32_16x16x32_bf16(af, bf, acc[nt], 0, 0, 0);
        }
    }

    float w20[4], w21[4];
    #pragma unroll
    for (int nt = 0; nt < 4; ++nt) {
        int o = nt * 16 + (lane & 15);
        w20[nt] = w2S[o * 2 + 0];
        w21[nt] = w2S[o * 2 + 1];
    }
    const float bias0 = b_e2[0], bias1 = b_e2[1];
    #pragma unroll
    for (int r = 0; r < 4; ++r) {
        float p0 = 0.f, p1 = 0.f;
        #pragma unroll
        for (int nt = 0; nt < 4; ++nt) {
            float z = fmaxf(acc[nt][r], 0.f);
            p0 = fmaf(z, w20[nt], p0);
            p1 = fmaf(z, w21[nt], p1);
        }
        #pragma unroll
        for (int off = 1; off < 16; off <<= 1) {
            p0 += __shfl_xor(p0, off);
            p1 += __shfl_xor(p1, off);
        }
        if ((lane & 15) == 0) {
            int e = e0 + w * 16 + (lane >> 4) * 4 + r;
            float2 v; v.x = p0 + bias0; v.y = p1 + bias1;
            ((float2*)out)[e] = v;
        }
    }
}

// ---------------------------------------------------------------------------
extern "C" void kernel_launch(void* const* d_in, const int* in_sizes, int n_in,
                              void* d_out, int out_size, void* d_ws, size_t ws_size,
                              hipStream_t stream) {
    const int*   ei        = (const int*)d_in[0];
    const float* edge_attr = (const float*)d_in[1];
    const float* node_emb  = (const float*)d_in[2];
    const float* w_nn      = (const float*)d_in[3];
    const float* b_nn      = (const float*)d_in[4];
    const float* root_w    = (const float*)d_in[5];
    const float* conv_bias = (const float*)d_in[6];
    const float* w_e1      = (const float*)d_in[7];
    const float* b_e1      = (const float*)d_in[8];
    const float* w_e2      = (const float*)d_in[9];
    const float* b_e2      = (const float*)d_in[10];
    float*       out       = (float*)d_out;
    float*       agg       = (float*)d_ws;                       // [N,64] f32 = 12.8 MB
    ushort*      bfrag     = (ushort*)((char*)d_ws + 12800000);  // 20480 B

    // K_P: pre-packed classifier B fragments
    k_prep<<<(5 * 4 * 64 * 8 + 255) / 256, 256, 0, stream>>>(w_e1, b_e1, bfrag);
    // K_A: agg = x @ root_w + conv_bias (fully rewrites region each call)
    k_init2<<<(NUM_NODES + 127) / 128, 256, 0, stream>>>(node_emb, root_w, conv_bias, agg);
    // K_B: fused edge-MLP + per-edge matvec + scatter-add; one wave per
    // 8-edge group (25000 waves) — r10 was grid-starved at 16 waves/CU.
    k_msg8<<<NUM_EDGES / MBX / 8, 512, 0, stream>>>(ei, edge_attr, node_emb, w_nn, b_nn, agg);
    // K_C: classifier GEMM
    k_edge3<<<NUM_EDGES / 64, 256, 0, stream>>>(ei, edge_attr, agg, bfrag, w_e2, b_e2, out);
}

// Round 12
// 144.613 us; speedup vs baseline: 1.0521x; 1.0521x over previous
//
#include <hip/hip_runtime.h>
#include <hip/hip_bf16.h>

#define NUM_NODES 50000
#define NODE_DIM 32
#define EDGE_DIM 7
#define HIDDEN_DIM 64
#define NUM_EDGES 200000

typedef __attribute__((ext_vector_type(8))) short bf16x8;
typedef __attribute__((ext_vector_type(4))) float f32x4;
typedef _Float16 h2 __attribute__((ext_vector_type(2)));

#if defined(__has_builtin)
#if __has_builtin(__builtin_amdgcn_fdot2)
#define HAVE_FDOT2 1
#endif
#endif
#ifndef HAVE_FDOT2
#define HAVE_FDOT2 0
#endif

__device__ inline unsigned f2bf(float f) {
    union { float f; unsigned u; } x; x.f = f;
    return (x.u + 0x7FFFu + ((x.u >> 16) & 1u)) >> 16;   // RNE
}
__device__ inline unsigned pack2bf(float a, float b) {
    return f2bf(a) | (f2bf(b) << 16);
}
__device__ inline h2 u2h(unsigned u) {
    union { unsigned u; h2 h; } c; c.u = u; return c.h;
}
__device__ inline unsigned h2u(h2 h) {
    union { h2 h; unsigned u; } c; c.h = h; return c.u;
}

// ---------------------------------------------------------------------------
// K_P: per-lane B fragments for the classifier GEMM (bf16, verified r4+).
// ---------------------------------------------------------------------------
__global__ __launch_bounds__(256) void k_prep(const float* __restrict__ w_e1,
                                              const float* __restrict__ b_e1,
                                              ushort* __restrict__ bfrag) {
    int u = blockIdx.x * blockDim.x + threadIdx.x;
    if (u < 5 * 4 * 64 * 8) {
        int j     = u & 7;
        int lane  = (u >> 3) & 63;
        int ntile = (u >> 9) & 3;
        int kstep = u >> 11;
        int k = kstep * 32 + (lane >> 4) * 8 + j;
        int o = ntile * 16 + (lane & 15);
        float v = (k < 135) ? w_e1[k * 64 + o] : ((k == 135) ? b_e1[o] : 0.f);
        bfrag[u] = (ushort)f2bf(v);
    }
}

// ---------------------------------------------------------------------------
// K_A: agg[n][o] = conv_bias[o] + sum_i x[n][i] * root_w[i][o]   (verified)
// ---------------------------------------------------------------------------
__global__ __launch_bounds__(256) void k_init2(const float* __restrict__ x,
                                               const float* __restrict__ root_w,
                                               const float* __restrict__ conv_bias,
                                               float* __restrict__ agg) {
    __shared__ float rw[NODE_DIM * HIDDEN_DIM];   // 8KB
    __shared__ float cb[HIDDEN_DIM];
    __shared__ float xS[128 * NODE_DIM];          // 16KB
    for (int t = threadIdx.x; t < NODE_DIM * HIDDEN_DIM; t += 256) rw[t] = root_w[t];
    if (threadIdx.x < HIDDEN_DIM) cb[threadIdx.x] = conv_bias[threadIdx.x];
    const int nb = blockIdx.x * 128;
    {
        const float4* xg = (const float4*)x;
        float4* xs4 = (float4*)xS;
        #pragma unroll
        for (int r = 0; r < 4; ++r) {
            int t = r * 256 + threadIdx.x;
            int gi = nb * (NODE_DIM / 4) + t;
            xs4[t] = (gi < NUM_NODES * (NODE_DIM / 4)) ? xg[gi] : make_float4(0.f, 0.f, 0.f, 0.f);
        }
    }
    __syncthreads();
    const int lane = threadIdx.x & 63;
    const int w    = threadIdx.x >> 6;
    for (int r = 0; r < 32; ++r) {
        const int n = nb + w * 32 + r;
        if (n >= NUM_NODES) break;                 // wave-uniform
        float acc = cb[lane];
        const float* xr = &xS[(w * 32 + r) * NODE_DIM];
        #pragma unroll
        for (int i = 0; i < NODE_DIM; ++i)
            acc = fmaf(xr[i], rw[i * HIDDEN_DIM + lane], acc);
        agg[n * HIDDEN_DIM + lane] = acc;
    }
}

// ---------------------------------------------------------------------------
// K_B v8 (r10-verbatim body, unroll 2; grid = 1024 blocks = 8192 waves so
// the 32-wave/CU residency cap is actually reachable while each wave still
// amortizes the LDS weight fill over ~3 groups; r11 showed 1-group blocks
// waste the fill, r10 showed 512 blocks starve dispatch at 16 waves/CU):
//  - weights+bias packed f16 in ONE 32KB LDS plane [32][64] of uint4;
//    conflict-free b128 reads (0 conflicts measured r10/r11);
//  - MLP dot via v_dot2_f32_f16 (f32 accumulate);
//  - no x/ea LDS staging: src AND dst ids -> SGPR via readfirstlane
//    (dst prefetch new this round: removes the cold VMEM dep at scatter);
//  - MB=8 edges/wave, grid-stride; 64-lane atomicAdd scatter.
// ---------------------------------------------------------------------------
#define MBX 8
__global__ __launch_bounds__(512) void k_msg8(const int* __restrict__ ei,
                                              const float* __restrict__ ea,
                                              const float* __restrict__ x,
                                              const float* __restrict__ w_nn,
                                              const float* __restrict__ b_nn,
                                              float* __restrict__ agg) {
    __shared__ uint4 wHu[NODE_DIM * HIDDEN_DIM];   // 2048 x 16B = 32KB
    for (int c = threadIdx.x; c < NODE_DIM * HIDDEN_DIM; c += 512) {
        h2 p0, p1, p2, p3;
        p0[0] = (_Float16)w_nn[0 * 2048 + c]; p0[1] = (_Float16)w_nn[1 * 2048 + c];
        p1[0] = (_Float16)w_nn[2 * 2048 + c]; p1[1] = (_Float16)w_nn[3 * 2048 + c];
        p2[0] = (_Float16)w_nn[4 * 2048 + c]; p2[1] = (_Float16)w_nn[5 * 2048 + c];
        p3[0] = (_Float16)w_nn[6 * 2048 + c]; p3[1] = (_Float16)b_nn[c];
        uint4 v; v.x = h2u(p0); v.y = h2u(p1); v.z = h2u(p2); v.w = h2u(p3);
        wHu[c] = v;
    }
    __syncthreads();

    const int lane   = threadIdx.x & 63;
    const int wave   = (blockIdx.x * blockDim.x + threadIdx.x) >> 6;
    const int nwaves = (gridDim.x * blockDim.x) >> 6;

    for (int e0 = wave * MBX; e0 < NUM_EDGES; e0 += nwaves * MBX) {
        // NUM_EDGES % 8 == 0, no tail.
        int sA[MBX], sD[MBX];
        #pragma unroll
        for (int m = 0; m < MBX; ++m) {
            sA[m] = __builtin_amdgcn_readfirstlane(ei[e0 + m]);               // uniform -> SGPR
            sD[m] = __builtin_amdgcn_readfirstlane(ei[NUM_EDGES + e0 + m]);   // dst prefetch
        }

#if HAVE_FDOT2
        h2 ev[MBX][4];
        #pragma unroll
        for (int m = 0; m < MBX; ++m) {
            const float* ep = ea + (size_t)(e0 + m) * EDGE_DIM;
            ev[m][0][0] = (_Float16)ep[0]; ev[m][0][1] = (_Float16)ep[1];
            ev[m][1][0] = (_Float16)ep[2]; ev[m][1][1] = (_Float16)ep[3];
            ev[m][2][0] = (_Float16)ep[4]; ev[m][2][1] = (_Float16)ep[5];
            ev[m][3][0] = (_Float16)ep[6]; ev[m][3][1] = (_Float16)1.0f;
        }
#else
        float evf[MBX][7];
        #pragma unroll
        for (int m = 0; m < MBX; ++m) {
            const float* ep = ea + (size_t)(e0 + m) * EDGE_DIM;
            #pragma unroll
            for (int k = 0; k < 7; ++k) evf[m][k] = ep[k];
        }
#endif

        float acc[MBX];
        #pragma unroll
        for (int m = 0; m < MBX; ++m) acc[m] = 0.f;

        #pragma unroll 2
        for (int i4 = 0; i4 < NODE_DIM / 4; ++i4) {
            float4 xv[MBX];
            #pragma unroll
            for (int m = 0; m < MBX; ++m)
                xv[m] = *(const float4*)(x + (size_t)sA[m] * NODE_DIM + i4 * 4); // uniform addr
            #pragma unroll
            for (int ii = 0; ii < 4; ++ii) {
                const int i = i4 * 4 + ii;
                const uint4 wv = wHu[i * HIDDEN_DIM + lane];     // b128, conflict-free
#if HAVE_FDOT2
                const h2 w0 = u2h(wv.x), w1 = u2h(wv.y), w2 = u2h(wv.z), w3 = u2h(wv.w);
                #pragma unroll
                for (int m = 0; m < MBX; ++m) {
                    float t = __builtin_amdgcn_fdot2(ev[m][0], w0,
                              __builtin_amdgcn_fdot2(ev[m][1], w1,
                              __builtin_amdgcn_fdot2(ev[m][2], w2,
                              __builtin_amdgcn_fdot2(ev[m][3], w3, 0.f, false),
                              false), false), false);
                    t = fmaxf(t, 0.f);
                    const float xc = (ii == 0) ? xv[m].x : (ii == 1) ? xv[m].y
                                   : (ii == 2) ? xv[m].z : xv[m].w;
                    acc[m] = fmaf(t, xc, acc[m]);
                }
#else
                float wf[8];
                { h2 a = u2h(wv.x), b = u2h(wv.y), c = u2h(wv.z), d = u2h(wv.w);
                  wf[0] = (float)a[0]; wf[1] = (float)a[1];
                  wf[2] = (float)b[0]; wf[3] = (float)b[1];
                  wf[4] = (float)c[0]; wf[5] = (float)c[1];
                  wf[6] = (float)d[0]; wf[7] = (float)d[1]; }
                #pragma unroll
                for (int m = 0; m < MBX; ++m) {
                    float t = wf[7];
                    #pragma unroll
                    for (int k = 0; k < 7; ++k) t = fmaf(evf[m][k], wf[k], t);
                    t = fmaxf(t, 0.f);
                    const float xc = (ii == 0) ? xv[m].x : (ii == 1) ? xv[m].y
                                   : (ii == 2) ? xv[m].z : xv[m].w;
                    acc[m] = fmaf(t, xc, acc[m]);
                }
#endif
            }
        }

        #pragma unroll
        for (int m = 0; m < MBX; ++m)
            atomicAdd(&agg[(size_t)sD[m] * HIDDEN_DIM + lane], acc[m]);
    }
}

// ---------------------------------------------------------------------------
// K_C v3: classifier as bf16 MFMA GEMM (verbatim, passing since round 4).
// ---------------------------------------------------------------------------
#define ASTRIDE 168
__global__ __launch_bounds__(256) void k_edge3(const int* __restrict__ ei,
                                               const float* __restrict__ ea,
                                               const float* __restrict__ agg,
                                               const ushort* __restrict__ bfrag,
                                               const float* __restrict__ w_e2,
                                               const float* __restrict__ b_e2,
                                               float* __restrict__ out) {
    __shared__ ushort aS[64 * ASTRIDE];   // 21504B
    __shared__ ushort bS[5 * 4 * 64 * 8]; // 20480B
    __shared__ float  w2S[128];
    {
        const uint4* g = (const uint4*)bfrag;
        uint4* s = (uint4*)bS;
        for (int t = threadIdx.x; t < 1280; t += 256) s[t] = g[t];
        if (threadIdx.x < 128) w2S[threadIdx.x] = w_e2[threadIdx.x];
    }
    const int e0 = blockIdx.x * 64;
    {
        const int el = threadIdx.x >> 2;
        const int q  = threadIdx.x & 3;
        const int e  = e0 + el;
        const int src = ei[e], dst = ei[NUM_EDGES + e];
        const float4* ps = (const float4*)(agg + (size_t)src * HIDDEN_DIM + q * 16);
        const float4* pd = (const float4*)(agg + (size_t)dst * HIDDEN_DIM + q * 16);
        unsigned* arow = (unsigned*)(aS + el * ASTRIDE);
        #pragma unroll
        for (int i = 0; i < 4; ++i) {
            float4 s = ps[i];
            arow[q * 8 + i * 2 + 0] = pack2bf(fmaxf(s.x, 0.f), fmaxf(s.y, 0.f));
            arow[q * 8 + i * 2 + 1] = pack2bf(fmaxf(s.z, 0.f), fmaxf(s.w, 0.f));
        }
        #pragma unroll
        for (int i = 0; i < 4; ++i) {
            float4 d = pd[i];
            arow[32 + q * 8 + i * 2 + 0] = pack2bf(fmaxf(d.x, 0.f), fmaxf(d.y, 0.f));
            arow[32 + q * 8 + i * 2 + 1] = pack2bf(fmaxf(d.z, 0.f), fmaxf(d.w, 0.f));
        }
        if (q == 0) {
            float ev[8];
            #pragma unroll
            for (int k = 0; k < EDGE_DIM; ++k) ev[k] = ea[e * EDGE_DIM + k];
            ev[7] = 1.0f;
            #pragma unroll
            for (int i = 0; i < 4; ++i)
                arow[64 + i] = pack2bf(ev[2 * i], ev[2 * i + 1]);
        } else {
            unsigned* z = arow + 64 + q * 4;
            z[0] = 0u; z[1] = 0u; z[2] = 0u; z[3] = 0u;
        }
    }
    __syncthreads();

    const int lane = threadIdx.x & 63;
    const int w    = threadIdx.x >> 6;
    f32x4 acc[4];
    #pragma unroll
    for (int nt = 0; nt < 4; ++nt) acc[nt] = (f32x4){0.f, 0.f, 0.f, 0.f};

    const ushort* arow = aS + (w * 16 + (lane & 15)) * ASTRIDE + (lane >> 4) * 8;
    #pragma unroll
    for (int ks = 0; ks < 5; ++ks) {
        bf16x8 af = *(const bf16x8*)(arow + ks * 32);
        #pragma unroll
        for (int nt = 0; nt < 4; ++nt) {
            bf16x8 bf = *(const bf16x8*)(bS + ((ks * 4 + nt) * 64 + lane) * 8);
            acc[nt] = __builtin_amdgcn_mfma_f32_16x16x32_bf16(af, bf, acc[nt], 0, 0, 0);
        }
    }

    float w20[4], w21[4];
    #pragma unroll
    for (int nt = 0; nt < 4; ++nt) {
        int o = nt * 16 + (lane & 15);
        w20[nt] = w2S[o * 2 + 0];
        w21[nt] = w2S[o * 2 + 1];
    }
    const float bias0 = b_e2[0], bias1 = b_e2[1];
    #pragma unroll
    for (int r = 0; r < 4; ++r) {
        float p0 = 0.f, p1 = 0.f;
        #pragma unroll
        for (int nt = 0; nt < 4; ++nt) {
            float z = fmaxf(acc[nt][r], 0.f);
            p0 = fmaf(z, w20[nt], p0);
            p1 = fmaf(z, w21[nt], p1);
        }
        #pragma unroll
        for (int off = 1; off < 16; off <<= 1) {
            p0 += __shfl_xor(p0, off);
            p1 += __shfl_xor(p1, off);
        }
        if ((lane & 15) == 0) {
            int e = e0 + w * 16 + (lane >> 4) * 4 + r;
            float2 v; v.x = p0 + bias0; v.y = p1 + bias1;
            ((float2*)out)[e] = v;
        }
    }
}

// ---------------------------------------------------------------------------
extern "C" void kernel_launch(void* const* d_in, const int* in_sizes, int n_in,
                              void* d_out, int out_size, void* d_ws, size_t ws_size,
                              hipStream_t stream) {
    const int*   ei        = (const int*)d_in[0];
    const float* edge_attr = (const float*)d_in[1];
    const float* node_emb  = (const float*)d_in[2];
    const float* w_nn      = (const float*)d_in[3];
    const float* b_nn      = (const float*)d_in[4];
    const float* root_w    = (const float*)d_in[5];
    const float* conv_bias = (const float*)d_in[6];
    const float* w_e1      = (const float*)d_in[7];
    const float* b_e1      = (const float*)d_in[8];
    const float* w_e2      = (const float*)d_in[9];
    const float* b_e2      = (const float*)d_in[10];
    float*       out       = (float*)d_out;
    float*       agg       = (float*)d_ws;                       // [N,64] f32 = 12.8 MB
    ushort*      bfrag     = (ushort*)((char*)d_ws + 12800000);  // 20480 B

    // K_P: pre-packed classifier B fragments
    k_prep<<<(5 * 4 * 64 * 8 + 255) / 256, 256, 0, stream>>>(w_e1, b_e1, bfrag);
    // K_A: agg = x @ root_w + conv_bias (fully rewrites region each call)
    k_init2<<<(NUM_NODES + 127) / 128, 256, 0, stream>>>(node_emb, root_w, conv_bias, agg);
    // K_B: fused edge-MLP + per-edge matvec + scatter-add.
    // 1024 blocks = 8192 waves: 32 waves/CU dispatched (residency cap),
    // LDS fill amortized over ~3 groups/wave (r10: starved; r11: 1-group fill waste).
    k_msg8<<<1024, 512, 0, stream>>>(ei, edge_attr, node_emb, w_nn, b_nn, agg);
    // K_C: classifier GEMM
    k_edge3<<<NUM_EDGES / 64, 256, 0, stream>>>(ei, edge_attr, agg, bfrag, w_e2, b_e2, out);
}